// Round 6
// baseline (511.834 us; speedup 1.0000x reference)
//
#include <hip/hip_runtime.h>
#include <math.h>

// kNN (B=1024, C=500000, D=64) + inverse-distance weighting, top-50.
// R6: convert_kernel pre-packs table to bf16 in MFMA-swizzled layout + exact
// row norms -> filter hot loop = 1 uint4 load + 1 b128 LDS write per thread
// per stage, double-buffered (1 barrier/iter). qthresh = 8 queries/block.
// select caches candidate list in LDS. Fallback to R5 filter if ws too small.

#define DELTA_SMOOTH 1e-3f
#define K_NEIGH 50
#define MAXCAP 8192
#define SAMPLE 2048
#define SAMPLE_TARGET 6
#define NBINS 256
#define MARGIN 0.75f       // bf16 dot worst-case error margin (d2 units)
#define MARGIN_Q 26        // select margin in d2q quanta: 2*(0.75+1/16)*16
#define RPB 1024           // table rows per filter block
#define QTILE 512          // queries per filter block (8 waves x 64)
#define SDEPTH 8           // LDS staging slots per (block,query); lambda~3
#define LW 768             // select rescore list size
#define QB 8               // queries per qthresh block
#define CVL 4096           // select LDS candidate cache

typedef __attribute__((ext_vector_type(8))) short short8;
typedef __attribute__((ext_vector_type(4))) float f32x4;

__device__ __forceinline__ unsigned f2bf(float f) {
  unsigned u = __float_as_uint(f);
  return ((u + 0x7fffu + ((u >> 16) & 1u)) >> 16) & 0xffffu;
}

// ---------------- Kernel 0: table -> bf16 swizzled tiles + row norms ----------------
// Layout: tile t = rows 64t..64t+63; row lr chunk c (8 bf16) stored at
// uint4 index t*512 + lr*8 + (c ^ (lr&7)).  Matches filter b-frag reads.
__global__ __launch_bounds__(256) void convert_kernel(
    const float* __restrict__ tk, uint4* __restrict__ tkbf,
    float* __restrict__ tnorm, int C, int padded) {
  int t = blockIdx.x * 256 + threadIdx.x;   // global chunk id
  int r = t >> 3;
  if (r >= padded) return;
  int c = t & 7;
  int rs = r < C ? r : C - 1;
  const float4* src = (const float4*)(tk + (size_t)rs * 64 + c * 8);
  float4 a = src[0], b = src[1];
  float sq = a.x * a.x + a.y * a.y + a.z * a.z + a.w * a.w
           + b.x * b.x + b.y * b.y + b.z * b.z + b.w * b.w;
  sq += __shfl_xor(sq, 1); sq += __shfl_xor(sq, 2); sq += __shfl_xor(sq, 4);
  if (c == 0) tnorm[r] = sq;
  uint4 u;
  u.x = f2bf(a.x) | (f2bf(a.y) << 16);
  u.y = f2bf(a.z) | (f2bf(a.w) << 16);
  u.z = f2bf(b.x) | (f2bf(b.y) << 16);
  u.w = f2bf(b.z) | (f2bf(b.w) << 16);
  int tile = r >> 6, lr = r & 63;
  tkbf[(size_t)tile * 512 + lr * 8 + (c ^ (lr & 7))] = u;
}

// ---------------- Kernel 1: per-query radius, 8 queries/block ----------------
__global__ __launch_bounds__(256) void qthresh_kernel(
    const float* __restrict__ keys, const float* __restrict__ tk,
    float* __restrict__ thr, float* __restrict__ qnorm, int C) {
  int q0 = blockIdx.x * QB;
  __shared__ __align__(16) float kq[QB * 64];
  __shared__ unsigned hist[QB][NBINS];
  __shared__ float qn8[QB];
  int tid = threadIdx.x;
  int lane = tid & 63;
  int wid = tid >> 6;
  for (int i = tid; i < QB * 64; i += 256) kq[i] = keys[(size_t)q0 * 64 + i];
  for (int i = tid; i < QB * NBINS; i += 256) (&hist[0][0])[i] = 0u;
  __syncthreads();
  if (tid < QB) {
    float s = 0.f;
    for (int j = 0; j < 64; ++j) { float v = kq[tid * 64 + j]; s += v * v; }
    qn8[tid] = s;
  }
  __syncthreads();
  int kc = lane & 3;
  const int SQ4 = SAMPLE >> 2;   // rows per wave
  for (int pass = 0; pass < 2; ++pass) {
    float4 kf[4][4];
    #pragma unroll
    for (int j = 0; j < 4; ++j)
      #pragma unroll
      for (int u = 0; u < 4; ++u)
        kf[j][u] = ((const float4*)kq)[(pass * 4 + j) * 16 + kc * 4 + u];
    for (int rr = (lane >> 2); rr < SQ4; rr += 16) {
      int r = wid * SQ4 + rr;
      const float4* trow = (const float4*)(tk + (size_t)r * 64 + kc * 16);
      float4 t0 = trow[0], t1 = trow[1], t2 = trow[2], t3 = trow[3];
      #pragma unroll
      for (int j = 0; j < 4; ++j) {
        float s = kf[j][0].x * t0.x + kf[j][0].y * t0.y + kf[j][0].z * t0.z + kf[j][0].w * t0.w
                + kf[j][1].x * t1.x + kf[j][1].y * t1.y + kf[j][1].z * t1.z + kf[j][1].w * t1.w
                + kf[j][2].x * t2.x + kf[j][2].y * t2.y + kf[j][2].z * t2.z + kf[j][2].w * t2.w
                + kf[j][3].x * t3.x + kf[j][3].y * t3.y + kf[j][3].z * t3.z + kf[j][3].w * t3.w;
        s += __shfl_xor(s, 1); s += __shfl_xor(s, 2);
        if (kc == 0) {
          int jq = pass * 4 + j;
          // qn + tn - 2*dot; tn recomputed cheaply from... use exact: need tn.
          // We don't have tnorm here (independent of convert) -> compute inline:
          // reuse t* regs:
          float tn = t0.x * t0.x + t0.y * t0.y + t0.z * t0.z + t0.w * t0.w
                   + t1.x * t1.x + t1.y * t1.y + t1.z * t1.z + t1.w * t1.w
                   + t2.x * t2.x + t2.y * t2.y + t2.z * t2.z + t2.w * t2.w
                   + t3.x * t3.x + t3.y * t3.y + t3.z * t3.z + t3.w * t3.w;
          // tn here is only this lane's quarter; need full row norm:
          // (handled below via shuffle before j-loop is wrong; instead do
          // the proper thing: compute tn once per row outside j-loop)
          (void)tn;
          float d2 = 0.f; (void)d2;
          // placeholder; real code below
          int b = 0; (void)b; (void)jq;
        }
      }
      // ---- real epilogue (tn computed once per row) ----
      float tnp = t0.x * t0.x + t0.y * t0.y + t0.z * t0.z + t0.w * t0.w
                + t1.x * t1.x + t1.y * t1.y + t1.z * t1.z + t1.w * t1.w
                + t2.x * t2.x + t2.y * t2.y + t2.z * t2.z + t2.w * t2.w
                + t3.x * t3.x + t3.y * t3.y + t3.z * t3.z + t3.w * t3.w;
      tnp += __shfl_xor(tnp, 1); tnp += __shfl_xor(tnp, 2);
      #pragma unroll
      for (int j = 0; j < 4; ++j) {
        float s = kf[j][0].x * t0.x + kf[j][0].y * t0.y + kf[j][0].z * t0.z + kf[j][0].w * t0.w
                + kf[j][1].x * t1.x + kf[j][1].y * t1.y + kf[j][1].z * t1.z + kf[j][1].w * t1.w
                + kf[j][2].x * t2.x + kf[j][2].y * t2.y + kf[j][2].z * t2.z + kf[j][2].w * t2.w
                + kf[j][3].x * t3.x + kf[j][3].y * t3.y + kf[j][3].z * t3.z + kf[j][3].w * t3.w;
        s += __shfl_xor(s, 1); s += __shfl_xor(s, 2);
        if (kc == 0) {
          int jq = pass * 4 + j;
          float d2 = qn8[jq] + tnp - 2.f * s;
          int b = (int)d2;
          b = b < 0 ? 0 : (b > NBINS - 1 ? NBINS - 1 : b);
          atomicAdd(&hist[jq][b], 1u);
        }
      }
    }
  }
  __syncthreads();
  if (tid < QB) {
    unsigned cum = 0; int bstar = NBINS - 1;
    for (int b = 0; b < NBINS; ++b) {
      cum += hist[tid][b];
      if (cum >= (unsigned)SAMPLE_TARGET) { bstar = b; break; }
    }
    thr[q0 + tid] = (float)(bstar + 1) + MARGIN - qn8[tid];
    qnorm[q0 + tid] = qn8[tid];
  }
}

// ---------------- Kernel 2a: FAST bf16 MFMA radius filter (pre-converted table) ----------------
__global__ __launch_bounds__(512, 4) void filter_mfma_fast(
    const uint4* __restrict__ tkbf, const float* __restrict__ keys,
    const float* __restrict__ tnorm, const float* __restrict__ thr,
    const float* __restrict__ qnorm, int* __restrict__ cnt,
    unsigned* __restrict__ candi, int C, int cap) {
  __shared__ float tnorm_lds[RPB];                        // 4 KB
  __shared__ float thr_lds[QTILE];                        // 2 KB
  __shared__ float qn_lds[QTILE];                         // 2 KB
  __shared__ unsigned scnt[QTILE];                        // 2 KB
  __shared__ unsigned sbuf[QTILE * SDEPTH];               // 16 KB
  __shared__ __align__(16) unsigned char bstage[2][64 * 128];  // 16 KB dbuf

  int tid = threadIdx.x;
  int qt = blockIdx.x & 1;
  int chunk = blockIdx.x >> 1;
  int qbase = qt * QTILE;
  int rstart = chunk * RPB;

  tnorm_lds[tid] = tnorm[rstart + tid];
  tnorm_lds[tid + 512] = tnorm[rstart + tid + 512];
  thr_lds[tid] = thr[qbase + tid];
  qn_lds[tid] = qnorm[qbase + tid];
  scnt[tid] = 0u;

  int lane = tid & 63;
  int wq = tid >> 6;
  int l15 = lane & 15;
  int quad = lane >> 4;

  // A fragments: 4 m-tiles; A[m=l15][k=s*32+quad*8+j] (verified R2-R5)
  short8 afrag[4][2];
  #pragma unroll
  for (int mt = 0; mt < 4; ++mt) {
    const float* kp = keys + (size_t)(qbase + wq * 64 + mt * 16 + l15) * 64 + quad * 8;
    #pragma unroll
    for (int s = 0; s < 2; ++s) {
      float4 x = *(const float4*)(kp + s * 32);
      float4 y = *(const float4*)(kp + s * 32 + 4);
      short8 a;
      a[0] = (short)f2bf(x.x); a[1] = (short)f2bf(x.y);
      a[2] = (short)f2bf(x.z); a[3] = (short)f2bf(x.w);
      a[4] = (short)f2bf(y.x); a[5] = (short)f2bf(y.y);
      a[6] = (short)f2bf(y.z); a[7] = (short)f2bf(y.w);
      afrag[mt][s] = a;
    }
  }

  // precheck constants: d2p < hq  <=>  max4(acc) > tn*0.5 - hq*0.5
  float th2[4];
  #pragma unroll
  for (int mt = 0; mt < 4; ++mt) {
    float h0 = thr_lds[wq * 64 + mt * 16 + quad * 4 + 0];
    float h1 = thr_lds[wq * 64 + mt * 16 + quad * 4 + 1];
    float h2 = thr_lds[wq * 64 + mt * 16 + quad * 4 + 2];
    float h3 = thr_lds[wq * 64 + mt * 16 + quad * 4 + 3];
    th2[mt] = fmaxf(fmaxf(h0, h1), fmaxf(h2, h3)) * 0.5f;
  }

  const int ITERS = RPB / 64;
  const uint4* gsrc = tkbf + (size_t)(rstart >> 6) * 512;
  uint4 pre = gsrc[tid];   // stage 0

  f32x4 zero4 = {0.f, 0.f, 0.f, 0.f};

  for (int it = 0; it < ITERS; ++it) {
    unsigned char* buf = bstage[it & 1];
    ((uint4*)buf)[tid] = pre;
    if (it + 1 < ITERS) pre = gsrc[(size_t)(it + 1) * 512 + tid];
    __syncthreads();
    #pragma unroll
    for (int half = 0; half < 2; ++half) {
      short8 b[2][2];
      #pragma unroll
      for (int tt = 0; tt < 2; ++tt) {
        int nloc = half * 32 + tt * 16 + l15;
        #pragma unroll
        for (int s = 0; s < 2; ++s) {
          int c = s * 4 + quad;
          unsigned addr = (unsigned)(nloc * 128 + ((c ^ (nloc & 7)) << 4));
          b[tt][s] = *(const short8*)(buf + addr);
        }
      }
      f32x4 acc[4][2];
      #pragma unroll
      for (int mt = 0; mt < 4; ++mt) {
        #pragma unroll
        for (int tt = 0; tt < 2; ++tt) {
          f32x4 a0 = __builtin_amdgcn_mfma_f32_16x16x32_bf16(afrag[mt][0], b[tt][0], zero4, 0, 0, 0);
          acc[mt][tt] = __builtin_amdgcn_mfma_f32_16x16x32_bf16(afrag[mt][1], b[tt][1], a0, 0, 0, 0);
        }
      }
      #pragma unroll
      for (int tt = 0; tt < 2; ++tt) {
        int rloc = it * 64 + half * 32 + tt * 16 + l15;
        float tn = tnorm_lds[rloc];
        float tnh = tn * 0.5f;
        int n = rstart + rloc;
        #pragma unroll
        for (int mt = 0; mt < 4; ++mt) {
          float mx4 = fmaxf(fmaxf(acc[mt][tt][0], acc[mt][tt][1]),
                            fmaxf(acc[mt][tt][2], acc[mt][tt][3]));
          if (mx4 > tnh - th2[mt]) {   // <=> min4(d2p) < quad-max thr
            #pragma unroll
            for (int r = 0; r < 4; ++r) {
              float d2p = fmaf(-2.f, acc[mt][tt][r], tn);
              int ql = wq * 64 + mt * 16 + quad * 4 + r;
              if (d2p < thr_lds[ql] && n < C) {
                float d2f = d2p + qn_lds[ql];
                int d2q = (int)(d2f * 16.f);
                d2q = d2q < 0 ? 0 : (d2q > 8191 ? 8191 : d2q);
                unsigned v = ((unsigned)d2q << 19) | (unsigned)n;
                unsigned p = atomicAdd(&scnt[ql], 1u);
                if (p < SDEPTH) {
                  sbuf[ql * SDEPTH + p] = v;
                } else {
                  int g = atomicAdd(&cnt[qbase + ql], 1);
                  if (g < cap) candi[(size_t)(qbase + ql) * cap + g] = v;
                }
              }
            }
          }
        }
      }
    }
    __syncthreads();
  }
  int m = (int)scnt[tid];
  if (m > SDEPTH) m = SDEPTH;
  if (m > 0) {
    int base = atomicAdd(&cnt[qbase + tid], m);
    for (int j = 0; j < m; ++j) {
      int g = base + j;
      if (g < cap) candi[(size_t)(qbase + tid) * cap + g] = sbuf[tid * SDEPTH + j];
    }
  }
}

// ---------------- Kernel 2b: FALLBACK filter (R5 verbatim; in-loop convert) ----------------
__global__ __launch_bounds__(512, 4) void filter_mfma_kernel(
    const float* __restrict__ keys, const float* __restrict__ tk,
    const float* __restrict__ thr, const float* __restrict__ qnorm,
    int* __restrict__ cnt, unsigned* __restrict__ candi, int C, int cap) {
  __shared__ float tnstage[64];
  __shared__ float thr_lds[QTILE];
  __shared__ float qn_lds[QTILE];
  __shared__ unsigned scnt[QTILE];
  __shared__ unsigned sbuf[QTILE * SDEPTH];
  __shared__ __align__(16) unsigned char bstage[64 * 128];

  int tid = threadIdx.x;
  int qt = blockIdx.x & 1;
  int chunk = blockIdx.x >> 1;
  int qbase = qt * QTILE;
  int rstart = chunk * RPB;

  thr_lds[tid] = thr[qbase + tid];
  qn_lds[tid] = qnorm[qbase + tid];
  scnt[tid] = 0u;

  int lane = tid & 63;
  int wq = tid >> 6;
  int l15 = lane & 15;
  int quad = lane >> 4;

  short8 afrag[4][2];
  #pragma unroll
  for (int mt = 0; mt < 4; ++mt) {
    const float* kp = keys + (size_t)(qbase + wq * 64 + mt * 16 + l15) * 64 + quad * 8;
    #pragma unroll
    for (int s = 0; s < 2; ++s) {
      float4 x = *(const float4*)(kp + s * 32);
      float4 y = *(const float4*)(kp + s * 32 + 4);
      short8 a;
      a[0] = (short)f2bf(x.x); a[1] = (short)f2bf(x.y);
      a[2] = (short)f2bf(x.z); a[3] = (short)f2bf(x.w);
      a[4] = (short)f2bf(y.x); a[5] = (short)f2bf(y.y);
      a[6] = (short)f2bf(y.z); a[7] = (short)f2bf(y.w);
      afrag[mt][s] = a;
    }
  }
  __syncthreads();

  float hq[4];
  #pragma unroll
  for (int mt = 0; mt < 4; ++mt) {
    float h0 = thr_lds[wq * 64 + mt * 16 + quad * 4 + 0];
    float h1 = thr_lds[wq * 64 + mt * 16 + quad * 4 + 1];
    float h2 = thr_lds[wq * 64 + mt * 16 + quad * 4 + 2];
    float h3 = thr_lds[wq * 64 + mt * 16 + quad * 4 + 3];
    hq[mt] = fmaxf(fmaxf(h0, h1), fmaxf(h2, h3));
  }

  int srow = tid >> 3;
  int scol = tid & 7;
  unsigned sbyte = (unsigned)(srow * 128 + ((scol ^ (srow & 7)) << 4));

  const int ITERS = RPB / 64;
  int r0 = rstart + srow; if (r0 > C - 1) r0 = C - 1;
  float4 pa = *(const float4*)(tk + (size_t)r0 * 64 + scol * 8);
  float4 pb = *(const float4*)(tk + (size_t)r0 * 64 + scol * 8 + 4);

  f32x4 zero4 = {0.f, 0.f, 0.f, 0.f};

  for (int it = 0; it < ITERS; ++it) {
    float part = pa.x * pa.x + pa.y * pa.y + pa.z * pa.z + pa.w * pa.w
               + pb.x * pb.x + pb.y * pb.y + pb.z * pb.z + pb.w * pb.w;
    part += __shfl_xor(part, 1);
    part += __shfl_xor(part, 2);
    part += __shfl_xor(part, 4);
    if ((tid & 7) == 0) tnstage[srow] = part;
    uint4 u;
    u.x = f2bf(pa.x) | (f2bf(pa.y) << 16);
    u.y = f2bf(pa.z) | (f2bf(pa.w) << 16);
    u.z = f2bf(pb.x) | (f2bf(pb.y) << 16);
    u.w = f2bf(pb.z) | (f2bf(pb.w) << 16);
    *(uint4*)(bstage + sbyte) = u;
    __syncthreads();
    if (it + 1 < ITERS) {
      int rn = rstart + (it + 1) * 64 + srow; if (rn > C - 1) rn = C - 1;
      pa = *(const float4*)(tk + (size_t)rn * 64 + scol * 8);
      pb = *(const float4*)(tk + (size_t)rn * 64 + scol * 8 + 4);
    }
    #pragma unroll
    for (int half = 0; half < 2; ++half) {
      short8 b[2][2];
      #pragma unroll
      for (int tt = 0; tt < 2; ++tt) {
        int nloc = half * 32 + tt * 16 + l15;
        #pragma unroll
        for (int s = 0; s < 2; ++s) {
          int c = s * 4 + quad;
          unsigned addr = (unsigned)(nloc * 128 + ((c ^ (nloc & 7)) << 4));
          b[tt][s] = *(const short8*)(bstage + addr);
        }
      }
      f32x4 acc[4][2];
      #pragma unroll
      for (int mt = 0; mt < 4; ++mt) {
        #pragma unroll
        for (int tt = 0; tt < 2; ++tt) {
          f32x4 a0 = __builtin_amdgcn_mfma_f32_16x16x32_bf16(afrag[mt][0], b[tt][0], zero4, 0, 0, 0);
          acc[mt][tt] = __builtin_amdgcn_mfma_f32_16x16x32_bf16(afrag[mt][1], b[tt][1], a0, 0, 0, 0);
        }
      }
      #pragma unroll
      for (int tt = 0; tt < 2; ++tt) {
        float tn = tnstage[half * 32 + tt * 16 + l15];
        int n = rstart + it * 64 + half * 32 + tt * 16 + l15;
        #pragma unroll
        for (int mt = 0; mt < 4; ++mt) {
          float d0 = fmaf(-2.f, acc[mt][tt][0], tn);
          float d1 = fmaf(-2.f, acc[mt][tt][1], tn);
          float d2 = fmaf(-2.f, acc[mt][tt][2], tn);
          float d3 = fmaf(-2.f, acc[mt][tt][3], tn);
          float mn4 = fminf(fminf(d0, d1), fminf(d2, d3));
          if (mn4 < hq[mt]) {
            float dd[4] = {d0, d1, d2, d3};
            #pragma unroll
            for (int r = 0; r < 4; ++r) {
              int ql = wq * 64 + mt * 16 + quad * 4 + r;
              if (dd[r] < thr_lds[ql] && n < C) {
                float d2f = dd[r] + qn_lds[ql];
                int d2q = (int)(d2f * 16.f);
                d2q = d2q < 0 ? 0 : (d2q > 8191 ? 8191 : d2q);
                unsigned v = ((unsigned)d2q << 19) | (unsigned)n;
                unsigned p = atomicAdd(&scnt[ql], 1u);
                if (p < SDEPTH) {
                  sbuf[ql * SDEPTH + p] = v;
                } else {
                  int g = atomicAdd(&cnt[qbase + ql], 1);
                  if (g < cap) candi[(size_t)(qbase + ql) * cap + g] = v;
                }
              }
            }
          }
        }
      }
    }
    __syncthreads();
  }
  int m = (int)scnt[tid];
  if (m > SDEPTH) m = SDEPTH;
  if (m > 0) {
    int base = atomicAdd(&cnt[qbase + tid], m);
    for (int j = 0; j < m; ++j) {
      int g = base + j;
      if (g < cap) candi[(size_t)(qbase + tid) * cap + g] = sbuf[tid * SDEPTH + j];
    }
  }
}

// ---------------- Kernel 3: select (LDS-cached list) ----------------
__global__ __launch_bounds__(256) void select_kernel(
    const float* __restrict__ keys, const float* __restrict__ tk,
    const float* __restrict__ tv, const int* __restrict__ cnt,
    const unsigned* __restrict__ candi, float* __restrict__ out, int cap) {
  int q = blockIdx.x;
  __shared__ unsigned cvl[CVL];
  __shared__ unsigned hist[NBINS];
  __shared__ unsigned wsum[4];
  __shared__ unsigned minq_sh;
  __shared__ int b50_sh;
  __shared__ int lidx[LW];
  __shared__ unsigned ed2[LW];
  __shared__ int m_sh;
  __shared__ float redw[4], redwv[4];
  int tid = threadIdx.x;
  int lane = tid & 63;
  int wid = tid >> 6;
  int n = cnt[q];
  if (n > cap) n = cap;
  hist[tid] = 0u;
  if (tid == 0) { minq_sh = 0xffffffffu; b50_sh = NBINS - 1; m_sh = 0; }
  __syncthreads();
  const unsigned* cv = candi + (size_t)q * cap;
  // phase A0: load + cache + min
  unsigned mn = 0xffffffffu;
  for (int i = tid; i < n; i += 256) {
    unsigned v = cv[i];
    if (i < CVL) cvl[i] = v;
    unsigned d = v >> 19; if (d < mn) mn = d;
  }
  #pragma unroll
  for (int off = 1; off < 64; off <<= 1) { unsigned o = __shfl_xor(mn, off); if (o < mn) mn = o; }
  if (lane == 0) atomicMin(&minq_sh, mn);
  __syncthreads();
  unsigned base = minq_sh;
  // phase A1: fine histogram (LDS source)
  for (int i = tid; i < n; i += 256) {
    unsigned v = (i < CVL) ? cvl[i] : cv[i];
    unsigned d = (v >> 19) - base;
    unsigned b = d >> 1; if (b > NBINS - 1) b = NBINS - 1;
    atomicAdd(&hist[b], 1u);
  }
  __syncthreads();
  unsigned h = hist[tid];
  unsigned p = h;
  #pragma unroll
  for (int off = 1; off < 64; off <<= 1) {
    unsigned v = __shfl_up(p, off);
    if (lane >= off) p += v;
  }
  if (lane == 63) wsum[wid] = p;
  __syncthreads();
  unsigned add = 0;
  for (int w2 = 0; w2 < wid; ++w2) add += wsum[w2];
  p += add;
  if (p >= (unsigned)K_NEIGH && p - h < (unsigned)K_NEIGH) b50_sh = tid;
  __syncthreads();
  unsigned Tq = base + (((unsigned)(b50_sh + 1)) << 1) + MARGIN_Q;
  // phase B: compact
  for (int i = tid; i < n; i += 256) {
    unsigned v = (i < CVL) ? cvl[i] : cv[i];
    if ((v >> 19) <= Tq) {
      int p2 = atomicAdd(&m_sh, 1);
      if (p2 < LW) lidx[p2] = (int)(v & 0x7ffffu);
    }
  }
  __syncthreads();
  int m = m_sh; if (m > LW) m = LW;
  // phase C: exact fp32 rescore (wave per candidate, 4x ILP)
  float kqv = keys[(size_t)q * 64 + lane];
  for (int i0 = wid * 4; i0 < m; i0 += 16) {
    int mm = m - i0; if (mm > 4) mm = 4;
    int idx[4]; float t[4];
    for (int u = 0; u < mm; ++u) idx[u] = lidx[i0 + u];
    for (int u = 0; u < mm; ++u) t[u] = tk[(size_t)idx[u] * 64 + lane];
    for (int u = 0; u < mm; ++u) {
      float d = t[u] - kqv;
      float s = d * d;
      #pragma unroll
      for (int off = 1; off < 64; off <<= 1) s += __shfl_xor(s, off);
      if (lane == 0) ed2[i0 + u] = __float_as_uint(s);
    }
  }
  __syncthreads();
  // phase D: rank via all-pairs count; rank<50 contributes (ties by row idx)
  float accw = 0.f, accwv = 0.f;
  for (int i = tid; i < m; i += 256) {
    unsigned long long key = ((unsigned long long)ed2[i] << 19) | (unsigned)lidx[i];
    int rank = 0;
    for (int j = 0; j < m; ++j) {
      unsigned long long kj = ((unsigned long long)ed2[j] << 19) | (unsigned)lidx[j];
      rank += (kj < key) ? 1 : 0;
    }
    if (rank < K_NEIGH) {
      float d2 = __uint_as_float(ed2[i]);
      float w = 1.f / (d2 + DELTA_SMOOTH);
      accw += w;
      accwv += w * tv[lidx[i]];
    }
  }
  #pragma unroll
  for (int off = 1; off < 64; off <<= 1) {
    accw += __shfl_xor(accw, off);
    accwv += __shfl_xor(accwv, off);
  }
  if (lane == 0) { redw[wid] = accw; redwv[wid] = accwv; }
  __syncthreads();
  if (tid == 0) {
    float sw = redw[0] + redw[1] + redw[2] + redw[3];
    float swv = redwv[0] + redwv[1] + redwv[2] + redwv[3];
    out[q] = swv / sw;
  }
}

extern "C" void kernel_launch(void* const* d_in, const int* in_sizes, int n_in,
                              void* d_out, int out_size, void* d_ws, size_t ws_size,
                              hipStream_t stream) {
  const float* keys = (const float*)d_in[0];   // [B,64]
  const float* tk   = (const float*)d_in[1];   // [C,64]
  const float* tv   = (const float*)d_in[2];   // [C]
  float* out = (float*)d_out;
  int B = in_sizes[0] / 64;   // 1024
  int C = in_sizes[2];        // 500000 (< 2^19 for packing)

  int nchunks = (C + RPB - 1) / RPB;
  int padded = nchunks * RPB;

  // common small buffers
  char* w = (char*)d_ws;
  float* thr = (float*)w;  w += (size_t)B * 4;
  float* qn  = (float*)w;  w += (size_t)B * 4;
  int*   cnt = (int*)w;    w += (size_t)B * 4;

  size_t fixed = (size_t)(w - (char*)d_ws);
  size_t fast_need = fixed + (size_t)padded * 128 + (size_t)padded * 4
                   + 2048ull * (size_t)B * 4;
  bool fast = ws_size >= fast_need;

  hipMemsetAsync(cnt, 0, (size_t)B * 4, stream);
  qthresh_kernel<<<B / QB, 256, 0, stream>>>(keys, tk, thr, qn, C);

  if (fast) {
    uint4* tkbf   = (uint4*)w;            w += (size_t)padded * 128;
    float* tnorm  = (float*)w;            w += (size_t)padded * 4;
    size_t used = (size_t)(w - (char*)d_ws);
    int cap = (int)((ws_size - used) / (4ull * (size_t)B));
    if (cap > MAXCAP) cap = MAXCAP;
    unsigned* candi = (unsigned*)w;
    convert_kernel<<<padded / 32, 256, 0, stream>>>(tk, tkbf, tnorm, C, padded);
    filter_mfma_fast<<<nchunks * 2, 512, 0, stream>>>(tkbf, keys, tnorm, thr, qn,
                                                      cnt, candi, C, cap);
    select_kernel<<<B, 256, 0, stream>>>(keys, tk, tv, cnt, candi, out, cap);
  } else {
    size_t used = fixed;
    int cap = (int)((ws_size - used) / (4ull * (size_t)B));
    if (cap > MAXCAP) cap = MAXCAP;
    if (cap < 1) cap = 1;
    unsigned* candi = (unsigned*)w;
    filter_mfma_kernel<<<nchunks * 2, 512, 0, stream>>>(keys, tk, thr, qn,
                                                        cnt, candi, C, cap);
    select_kernel<<<B, 256, 0, stream>>>(keys, tk, tv, cnt, candi, out, cap);
  }
}

// Round 7
// 492.718 us; speedup vs baseline: 1.0388x; 1.0388x over previous
//
#include <hip/hip_runtime.h>
#include <math.h>

// kNN (B=1024, C=500000, D=64) + inverse-distance weighting, top-50.
// R7: barrier-free MFMA filter. convert_kernel pre-packs table to bf16 in a
// fragment-direct layout (+ halved row norms); the filter loads B fragments
// straight from global (L1/L2-resident, 16 fully-used lines per load) -> no
// LDS staging, no barriers in the K-loop. Thresholds live in registers.
// qthresh reverted to R5 (R6's had dead-code double work). select = R6.

#define DELTA_SMOOTH 1e-3f
#define K_NEIGH 50
#define MAXCAP 8192
#define SAMPLE 2048
#define SAMPLE_TARGET 6
#define NBINS 256
#define MARGIN 0.75f       // bf16 dot worst-case error margin (d2 units)
#define MARGIN_Q 26        // select margin in d2q quanta: 2*(0.75+1/16)*16
#define RPB 1024           // table rows per filter block
#define QTILE 512          // queries per filter block (8 waves x 64)
#define SDEPTH 8           // LDS staging slots per (block,query); lambda~3
#define LW 768             // select rescore list size
#define CVL 4096           // select LDS candidate cache

typedef __attribute__((ext_vector_type(8))) short short8;
typedef __attribute__((ext_vector_type(4))) float f32x4;

__device__ __forceinline__ unsigned f2bf(float f) {
  unsigned u = __float_as_uint(f);
  return ((u + 0x7fffu + ((u >> 16) & 1u)) >> 16) & 0xffffu;
}

// ---------------- Kernel 0: table -> bf16 fragment-direct tiles + halved norms ----------------
// tile t = rows 64t..64t+63; uint4 index = r*8 + c  (identity: coalesced
// write).  Filter lane (l15,quad) reads idx = tile*512 + nloc*8 + (s*4+quad),
// nloc = half*32+tt*16+l15 -> for fixed (half,tt,s) the wave consumes 16 full
// 64B lines.  tnh2[r] = 0.5*||row r||^2.
__global__ __launch_bounds__(256) void convert_kernel(
    const float* __restrict__ tk, uint4* __restrict__ tkbf,
    float* __restrict__ tnh2, int C, int padded) {
  int t = blockIdx.x * 256 + threadIdx.x;   // global chunk id
  int r = t >> 3;
  if (r >= padded) return;
  int c = t & 7;
  int rs = r < C ? r : C - 1;
  const float4* src = (const float4*)(tk + (size_t)rs * 64 + c * 8);
  float4 a = src[0], b = src[1];
  float sq = a.x * a.x + a.y * a.y + a.z * a.z + a.w * a.w
           + b.x * b.x + b.y * b.y + b.z * b.z + b.w * b.w;
  sq += __shfl_xor(sq, 1); sq += __shfl_xor(sq, 2); sq += __shfl_xor(sq, 4);
  if (c == 0) tnh2[r] = sq * 0.5f;
  uint4 u;
  u.x = f2bf(a.x) | (f2bf(a.y) << 16);
  u.y = f2bf(a.z) | (f2bf(a.w) << 16);
  u.z = f2bf(b.x) | (f2bf(b.y) << 16);
  u.w = f2bf(b.z) | (f2bf(b.w) << 16);
  tkbf[t] = u;
}

// ---------------- Kernel 1: per-query radius (R5 version) ----------------
__global__ __launch_bounds__(256) void qthresh_kernel(
    const float* __restrict__ keys, const float* __restrict__ tk,
    float* __restrict__ thr, float* __restrict__ qnorm, int C) {
  int q = blockIdx.x;
  __shared__ __align__(16) float kq[64];
  __shared__ unsigned hist[NBINS];
  __shared__ float qn_sh;
  __shared__ unsigned wsum[4];
  __shared__ int bstar_sh;
  int tid = threadIdx.x;
  int lane = tid & 63;
  int wid = tid >> 6;
  if (tid < 64) kq[tid] = keys[(size_t)q * 64 + tid];
  hist[tid] = 0u;
  if (tid == 0) bstar_sh = NBINS - 1;
  __syncthreads();
  if (tid < 64) {
    float v = kq[tid];
    float s = v * v;
    #pragma unroll
    for (int off = 32; off > 0; off >>= 1) s += __shfl_down(s, off);
    if (tid == 0) qn_sh = s;
  }
  __syncthreads();
  float qn = qn_sh;
  int kc = lane & 3;
  const float4* kq4 = (const float4*)kq;
  float4 kf[4];
  #pragma unroll
  for (int j = 0; j < 4; ++j) kf[j] = kq4[kc * 4 + j];
  int S = SAMPLE < C ? SAMPLE : C;
  for (int r = wid * (S >> 2) + (lane >> 2); r < (wid + 1) * (S >> 2); r += 16) {
    const float4* trow = (const float4*)(tk + (size_t)r * 64 + kc * 16);
    float a0 = 0.f, a1 = 0.f, sq = 0.f;
    #pragma unroll
    for (int j = 0; j < 4; ++j) {
      float4 tvv = trow[j];
      float4 kv = kf[j];
      a0 += kv.x * tvv.x + kv.y * tvv.y;
      a1 += kv.z * tvv.z + kv.w * tvv.w;
      sq += tvv.x * tvv.x + tvv.y * tvv.y + tvv.z * tvv.z + tvv.w * tvv.w;
    }
    float s = a0 + a1;
    s += __shfl_xor(s, 1); s += __shfl_xor(s, 2);
    sq += __shfl_xor(sq, 1); sq += __shfl_xor(sq, 2);
    if (kc == 0) {
      float d2 = qn + sq - 2.f * s;
      int b = (int)d2;
      b = b < 0 ? 0 : (b > NBINS - 1 ? NBINS - 1 : b);
      atomicAdd(&hist[b], 1u);
    }
  }
  __syncthreads();
  unsigned h = hist[tid];
  unsigned p = h;
  #pragma unroll
  for (int off = 1; off < 64; off <<= 1) {
    unsigned v = __shfl_up(p, off);
    if (lane >= off) p += v;
  }
  if (lane == 63) wsum[wid] = p;
  __syncthreads();
  unsigned add = 0;
  for (int w2 = 0; w2 < wid; ++w2) add += wsum[w2];
  p += add;
  if (p >= (unsigned)SAMPLE_TARGET && p - h < (unsigned)SAMPLE_TARGET) bstar_sh = tid;
  __syncthreads();
  if (tid == 0) {
    thr[q] = (float)(bstar_sh + 1) + MARGIN - qn;
    qnorm[q] = qn;
  }
}

// ---------------- Kernel 2a: barrier-free bf16 MFMA radius filter ----------------
// 8 waves x 64 queries; per tile-iter: 8 coalesced global uint4 fragment
// loads (L1/L2-hit) + 32 MFMA + register-threshold epilogue.  No LDS in the
// K-loop except rare candidate appends.  hit <=> acc + thr/2 > tn/2.
__global__ __launch_bounds__(512, 4) void filter_mfma_fast(
    const uint4* __restrict__ tkbf, const float* __restrict__ keys,
    const float* __restrict__ tnh2, const float* __restrict__ thr,
    const float* __restrict__ qnorm, int* __restrict__ cnt,
    unsigned* __restrict__ candi, int C, int cap) {
  __shared__ float tnh_lds[RPB];                          // 4 KB (halved norms)
  __shared__ float thr_lds[QTILE];                        // 2 KB
  __shared__ float qn_lds[QTILE];                         // 2 KB
  __shared__ unsigned scnt[QTILE];                        // 2 KB
  __shared__ unsigned sbuf[QTILE * SDEPTH];               // 16 KB

  int tid = threadIdx.x;
  int qt = blockIdx.x & 1;
  int chunk = blockIdx.x >> 1;
  int qbase = qt * QTILE;
  int rstart = chunk * RPB;

  tnh_lds[tid] = tnh2[rstart + tid];
  tnh_lds[tid + 512] = tnh2[rstart + tid + 512];
  thr_lds[tid] = thr[qbase + tid];
  qn_lds[tid] = qnorm[qbase + tid];
  scnt[tid] = 0u;

  int lane = tid & 63;
  int wq = tid >> 6;
  int l15 = lane & 15;
  int quad = lane >> 4;

  // A fragments: 4 m-tiles; A[m=l15][k=s*32+quad*8+j] (verified R2-R6)
  short8 afrag[4][2];
  #pragma unroll
  for (int mt = 0; mt < 4; ++mt) {
    const float* kp = keys + (size_t)(qbase + wq * 64 + mt * 16 + l15) * 64 + quad * 8;
    #pragma unroll
    for (int s = 0; s < 2; ++s) {
      float4 x = *(const float4*)(kp + s * 32);
      float4 y = *(const float4*)(kp + s * 32 + 4);
      short8 a;
      a[0] = (short)f2bf(x.x); a[1] = (short)f2bf(x.y);
      a[2] = (short)f2bf(x.z); a[3] = (short)f2bf(x.w);
      a[4] = (short)f2bf(y.x); a[5] = (short)f2bf(y.y);
      a[6] = (short)f2bf(y.z); a[7] = (short)f2bf(y.w);
      afrag[mt][s] = a;
    }
  }
  __syncthreads();   // all shared preloads visible before register reads

  // per-lane halved thresholds in registers (no LDS in hit path)
  float htr[4][4], hmax[4];
  #pragma unroll
  for (int mt = 0; mt < 4; ++mt) {
    #pragma unroll
    for (int r = 0; r < 4; ++r)
      htr[mt][r] = thr_lds[wq * 64 + mt * 16 + quad * 4 + r] * 0.5f;
    hmax[mt] = fmaxf(fmaxf(htr[mt][0], htr[mt][1]), fmaxf(htr[mt][2], htr[mt][3]));
  }

  int lbase = l15 * 8 + quad;
  const uint4* gt = tkbf + (size_t)(rstart >> 6) * 512 + lbase;

  f32x4 zero4 = {0.f, 0.f, 0.f, 0.f};
  const int ITERS = RPB / 64;

  for (int it = 0; it < ITERS; ++it) {
    const uint4* tp = gt + it * 512;
    #pragma unroll
    for (int half = 0; half < 2; ++half) {
      // B fragments straight from global: idx = nloc*8 + (s*4+quad)
      short8 b[2][2];
      #pragma unroll
      for (int tt = 0; tt < 2; ++tt)
        #pragma unroll
        for (int s = 0; s < 2; ++s)
          b[tt][s] = *(const short8*)(tp + half * 256 + tt * 128 + s * 4);
      f32x4 acc[4][2];
      #pragma unroll
      for (int mt = 0; mt < 4; ++mt) {
        #pragma unroll
        for (int tt = 0; tt < 2; ++tt) {
          f32x4 a0 = __builtin_amdgcn_mfma_f32_16x16x32_bf16(afrag[mt][0], b[tt][0], zero4, 0, 0, 0);
          acc[mt][tt] = __builtin_amdgcn_mfma_f32_16x16x32_bf16(afrag[mt][1], b[tt][1], a0, 0, 0, 0);
        }
      }
      #pragma unroll
      for (int tt = 0; tt < 2; ++tt) {
        int rloc = it * 64 + half * 32 + tt * 16 + l15;
        float tnh = tnh_lds[rloc];
        int n = rstart + rloc;
        #pragma unroll
        for (int mt = 0; mt < 4; ++mt) {
          float mx4 = fmaxf(fmaxf(acc[mt][tt][0], acc[mt][tt][1]),
                            fmaxf(acc[mt][tt][2], acc[mt][tt][3]));
          if (mx4 + hmax[mt] > tnh) {
            #pragma unroll
            for (int r = 0; r < 4; ++r) {
              if (acc[mt][tt][r] + htr[mt][r] > tnh && n < C) {
                int ql = wq * 64 + mt * 16 + quad * 4 + r;
                float d2f = 2.f * (tnh - acc[mt][tt][r]) + qn_lds[ql];
                int d2q = (int)(d2f * 16.f);
                d2q = d2q < 0 ? 0 : (d2q > 8191 ? 8191 : d2q);
                unsigned v = ((unsigned)d2q << 19) | (unsigned)n;
                unsigned p = atomicAdd(&scnt[ql], 1u);
                if (p < SDEPTH) {
                  sbuf[ql * SDEPTH + p] = v;
                } else {
                  int g = atomicAdd(&cnt[qbase + ql], 1);
                  if (g < cap) candi[(size_t)(qbase + ql) * cap + g] = v;
                }
              }
            }
          }
        }
      }
    }
  }
  __syncthreads();
  int m = (int)scnt[tid];
  if (m > SDEPTH) m = SDEPTH;
  if (m > 0) {
    int base = atomicAdd(&cnt[qbase + tid], m);
    for (int j = 0; j < m; ++j) {
      int g = base + j;
      if (g < cap) candi[(size_t)(qbase + tid) * cap + g] = sbuf[tid * SDEPTH + j];
    }
  }
}

// ---------------- Kernel 2b: FALLBACK filter (R5 verbatim; in-loop convert) ----------------
__global__ __launch_bounds__(512, 4) void filter_mfma_kernel(
    const float* __restrict__ keys, const float* __restrict__ tk,
    const float* __restrict__ thr, const float* __restrict__ qnorm,
    int* __restrict__ cnt, unsigned* __restrict__ candi, int C, int cap) {
  __shared__ float tnstage[64];
  __shared__ float thr_lds[QTILE];
  __shared__ float qn_lds[QTILE];
  __shared__ unsigned scnt[QTILE];
  __shared__ unsigned sbuf[QTILE * SDEPTH];
  __shared__ __align__(16) unsigned char bstage[64 * 128];

  int tid = threadIdx.x;
  int qt = blockIdx.x & 1;
  int chunk = blockIdx.x >> 1;
  int qbase = qt * QTILE;
  int rstart = chunk * RPB;

  thr_lds[tid] = thr[qbase + tid];
  qn_lds[tid] = qnorm[qbase + tid];
  scnt[tid] = 0u;

  int lane = tid & 63;
  int wq = tid >> 6;
  int l15 = lane & 15;
  int quad = lane >> 4;

  short8 afrag[4][2];
  #pragma unroll
  for (int mt = 0; mt < 4; ++mt) {
    const float* kp = keys + (size_t)(qbase + wq * 64 + mt * 16 + l15) * 64 + quad * 8;
    #pragma unroll
    for (int s = 0; s < 2; ++s) {
      float4 x = *(const float4*)(kp + s * 32);
      float4 y = *(const float4*)(kp + s * 32 + 4);
      short8 a;
      a[0] = (short)f2bf(x.x); a[1] = (short)f2bf(x.y);
      a[2] = (short)f2bf(x.z); a[3] = (short)f2bf(x.w);
      a[4] = (short)f2bf(y.x); a[5] = (short)f2bf(y.y);
      a[6] = (short)f2bf(y.z); a[7] = (short)f2bf(y.w);
      afrag[mt][s] = a;
    }
  }
  __syncthreads();

  float hq[4];
  #pragma unroll
  for (int mt = 0; mt < 4; ++mt) {
    float h0 = thr_lds[wq * 64 + mt * 16 + quad * 4 + 0];
    float h1 = thr_lds[wq * 64 + mt * 16 + quad * 4 + 1];
    float h2 = thr_lds[wq * 64 + mt * 16 + quad * 4 + 2];
    float h3 = thr_lds[wq * 64 + mt * 16 + quad * 4 + 3];
    hq[mt] = fmaxf(fmaxf(h0, h1), fmaxf(h2, h3));
  }

  int srow = tid >> 3;
  int scol = tid & 7;
  unsigned sbyte = (unsigned)(srow * 128 + ((scol ^ (srow & 7)) << 4));

  const int ITERS = RPB / 64;
  int r0 = rstart + srow; if (r0 > C - 1) r0 = C - 1;
  float4 pa = *(const float4*)(tk + (size_t)r0 * 64 + scol * 8);
  float4 pb = *(const float4*)(tk + (size_t)r0 * 64 + scol * 8 + 4);

  f32x4 zero4 = {0.f, 0.f, 0.f, 0.f};

  for (int it = 0; it < ITERS; ++it) {
    float part = pa.x * pa.x + pa.y * pa.y + pa.z * pa.z + pa.w * pa.w
               + pb.x * pb.x + pb.y * pb.y + pb.z * pb.z + pb.w * pb.w;
    part += __shfl_xor(part, 1);
    part += __shfl_xor(part, 2);
    part += __shfl_xor(part, 4);
    if ((tid & 7) == 0) tnstage[srow] = part;
    uint4 u;
    u.x = f2bf(pa.x) | (f2bf(pa.y) << 16);
    u.y = f2bf(pa.z) | (f2bf(pa.w) << 16);
    u.z = f2bf(pb.x) | (f2bf(pb.y) << 16);
    u.w = f2bf(pb.z) | (f2bf(pb.w) << 16);
    *(uint4*)(bstage + sbyte) = u;
    __syncthreads();
    if (it + 1 < ITERS) {
      int rn = rstart + (it + 1) * 64 + srow; if (rn > C - 1) rn = C - 1;
      pa = *(const float4*)(tk + (size_t)rn * 64 + scol * 8);
      pb = *(const float4*)(tk + (size_t)rn * 64 + scol * 8 + 4);
    }
    #pragma unroll
    for (int half = 0; half < 2; ++half) {
      short8 b[2][2];
      #pragma unroll
      for (int tt = 0; tt < 2; ++tt) {
        int nloc = half * 32 + tt * 16 + l15;
        #pragma unroll
        for (int s = 0; s < 2; ++s) {
          int c = s * 4 + quad;
          unsigned addr = (unsigned)(nloc * 128 + ((c ^ (nloc & 7)) << 4));
          b[tt][s] = *(const short8*)(bstage + addr);
        }
      }
      f32x4 acc[4][2];
      #pragma unroll
      for (int mt = 0; mt < 4; ++mt) {
        #pragma unroll
        for (int tt = 0; tt < 2; ++tt) {
          f32x4 a0 = __builtin_amdgcn_mfma_f32_16x16x32_bf16(afrag[mt][0], b[tt][0], zero4, 0, 0, 0);
          acc[mt][tt] = __builtin_amdgcn_mfma_f32_16x16x32_bf16(afrag[mt][1], b[tt][1], a0, 0, 0, 0);
        }
      }
      #pragma unroll
      for (int tt = 0; tt < 2; ++tt) {
        float tn = tnstage[half * 32 + tt * 16 + l15];
        int n = rstart + it * 64 + half * 32 + tt * 16 + l15;
        #pragma unroll
        for (int mt = 0; mt < 4; ++mt) {
          float d0 = fmaf(-2.f, acc[mt][tt][0], tn);
          float d1 = fmaf(-2.f, acc[mt][tt][1], tn);
          float d2 = fmaf(-2.f, acc[mt][tt][2], tn);
          float d3 = fmaf(-2.f, acc[mt][tt][3], tn);
          float mn4 = fminf(fminf(d0, d1), fminf(d2, d3));
          if (mn4 < hq[mt]) {
            float dd[4] = {d0, d1, d2, d3};
            #pragma unroll
            for (int r = 0; r < 4; ++r) {
              int ql = wq * 64 + mt * 16 + quad * 4 + r;
              if (dd[r] < thr_lds[ql] && n < C) {
                float d2f = dd[r] + qn_lds[ql];
                int d2q = (int)(d2f * 16.f);
                d2q = d2q < 0 ? 0 : (d2q > 8191 ? 8191 : d2q);
                unsigned v = ((unsigned)d2q << 19) | (unsigned)n;
                unsigned p = atomicAdd(&scnt[ql], 1u);
                if (p < SDEPTH) {
                  sbuf[ql * SDEPTH + p] = v;
                } else {
                  int g = atomicAdd(&cnt[qbase + ql], 1);
                  if (g < cap) candi[(size_t)(qbase + ql) * cap + g] = v;
                }
              }
            }
          }
        }
      }
    }
    __syncthreads();
  }
  int m = (int)scnt[tid];
  if (m > SDEPTH) m = SDEPTH;
  if (m > 0) {
    int base = atomicAdd(&cnt[qbase + tid], m);
    for (int j = 0; j < m; ++j) {
      int g = base + j;
      if (g < cap) candi[(size_t)(qbase + tid) * cap + g] = sbuf[tid * SDEPTH + j];
    }
  }
}

// ---------------- Kernel 3: select (LDS-cached list; R6 version) ----------------
__global__ __launch_bounds__(256) void select_kernel(
    const float* __restrict__ keys, const float* __restrict__ tk,
    const float* __restrict__ tv, const int* __restrict__ cnt,
    const unsigned* __restrict__ candi, float* __restrict__ out, int cap) {
  int q = blockIdx.x;
  __shared__ unsigned cvl[CVL];
  __shared__ unsigned hist[NBINS];
  __shared__ unsigned wsum[4];
  __shared__ unsigned minq_sh;
  __shared__ int b50_sh;
  __shared__ int lidx[LW];
  __shared__ unsigned ed2[LW];
  __shared__ int m_sh;
  __shared__ float redw[4], redwv[4];
  int tid = threadIdx.x;
  int lane = tid & 63;
  int wid = tid >> 6;
  int n = cnt[q];
  if (n > cap) n = cap;
  hist[tid] = 0u;
  if (tid == 0) { minq_sh = 0xffffffffu; b50_sh = NBINS - 1; m_sh = 0; }
  __syncthreads();
  const unsigned* cv = candi + (size_t)q * cap;
  unsigned mn = 0xffffffffu;
  for (int i = tid; i < n; i += 256) {
    unsigned v = cv[i];
    if (i < CVL) cvl[i] = v;
    unsigned d = v >> 19; if (d < mn) mn = d;
  }
  #pragma unroll
  for (int off = 1; off < 64; off <<= 1) { unsigned o = __shfl_xor(mn, off); if (o < mn) mn = o; }
  if (lane == 0) atomicMin(&minq_sh, mn);
  __syncthreads();
  unsigned base = minq_sh;
  for (int i = tid; i < n; i += 256) {
    unsigned v = (i < CVL) ? cvl[i] : cv[i];
    unsigned d = (v >> 19) - base;
    unsigned b = d >> 1; if (b > NBINS - 1) b = NBINS - 1;
    atomicAdd(&hist[b], 1u);
  }
  __syncthreads();
  unsigned h = hist[tid];
  unsigned p = h;
  #pragma unroll
  for (int off = 1; off < 64; off <<= 1) {
    unsigned v = __shfl_up(p, off);
    if (lane >= off) p += v;
  }
  if (lane == 63) wsum[wid] = p;
  __syncthreads();
  unsigned add = 0;
  for (int w2 = 0; w2 < wid; ++w2) add += wsum[w2];
  p += add;
  if (p >= (unsigned)K_NEIGH && p - h < (unsigned)K_NEIGH) b50_sh = tid;
  __syncthreads();
  unsigned Tq = base + (((unsigned)(b50_sh + 1)) << 1) + MARGIN_Q;
  for (int i = tid; i < n; i += 256) {
    unsigned v = (i < CVL) ? cvl[i] : cv[i];
    if ((v >> 19) <= Tq) {
      int p2 = atomicAdd(&m_sh, 1);
      if (p2 < LW) lidx[p2] = (int)(v & 0x7ffffu);
    }
  }
  __syncthreads();
  int m = m_sh; if (m > LW) m = LW;
  float kqv = keys[(size_t)q * 64 + lane];
  for (int i0 = wid * 4; i0 < m; i0 += 16) {
    int mm = m - i0; if (mm > 4) mm = 4;
    int idx[4]; float t[4];
    for (int u = 0; u < mm; ++u) idx[u] = lidx[i0 + u];
    for (int u = 0; u < mm; ++u) t[u] = tk[(size_t)idx[u] * 64 + lane];
    for (int u = 0; u < mm; ++u) {
      float d = t[u] - kqv;
      float s = d * d;
      #pragma unroll
      for (int off = 1; off < 64; off <<= 1) s += __shfl_xor(s, off);
      if (lane == 0) ed2[i0 + u] = __float_as_uint(s);
    }
  }
  __syncthreads();
  float accw = 0.f, accwv = 0.f;
  for (int i = tid; i < m; i += 256) {
    unsigned long long key = ((unsigned long long)ed2[i] << 19) | (unsigned)lidx[i];
    int rank = 0;
    for (int j = 0; j < m; ++j) {
      unsigned long long kj = ((unsigned long long)ed2[j] << 19) | (unsigned)lidx[j];
      rank += (kj < key) ? 1 : 0;
    }
    if (rank < K_NEIGH) {
      float d2 = __uint_as_float(ed2[i]);
      float w = 1.f / (d2 + DELTA_SMOOTH);
      accw += w;
      accwv += w * tv[lidx[i]];
    }
  }
  #pragma unroll
  for (int off = 1; off < 64; off <<= 1) {
    accw += __shfl_xor(accw, off);
    accwv += __shfl_xor(accwv, off);
  }
  if (lane == 0) { redw[wid] = accw; redwv[wid] = accwv; }
  __syncthreads();
  if (tid == 0) {
    float sw = redw[0] + redw[1] + redw[2] + redw[3];
    float swv = redwv[0] + redwv[1] + redwv[2] + redwv[3];
    out[q] = swv / sw;
  }
}

extern "C" void kernel_launch(void* const* d_in, const int* in_sizes, int n_in,
                              void* d_out, int out_size, void* d_ws, size_t ws_size,
                              hipStream_t stream) {
  const float* keys = (const float*)d_in[0];   // [B,64]
  const float* tk   = (const float*)d_in[1];   // [C,64]
  const float* tv   = (const float*)d_in[2];   // [C]
  float* out = (float*)d_out;
  int B = in_sizes[0] / 64;   // 1024
  int C = in_sizes[2];        // 500000 (< 2^19 for packing)

  int nchunks = (C + RPB - 1) / RPB;
  int padded = nchunks * RPB;

  char* w = (char*)d_ws;
  float* thr = (float*)w;  w += (size_t)B * 4;
  float* qn  = (float*)w;  w += (size_t)B * 4;
  int*   cnt = (int*)w;    w += (size_t)B * 4;

  size_t fixed = (size_t)(w - (char*)d_ws);
  size_t fast_need = fixed + (size_t)padded * 128 + (size_t)padded * 4
                   + 2048ull * (size_t)B * 4;
  bool fast = ws_size >= fast_need;

  hipMemsetAsync(cnt, 0, (size_t)B * 4, stream);
  qthresh_kernel<<<B, 256, 0, stream>>>(keys, tk, thr, qn, C);

  if (fast) {
    uint4* tkbf  = (uint4*)w;             w += (size_t)padded * 128;
    float* tnh2  = (float*)w;             w += (size_t)padded * 4;
    size_t used = (size_t)(w - (char*)d_ws);
    int cap = (int)((ws_size - used) / (4ull * (size_t)B));
    if (cap > MAXCAP) cap = MAXCAP;
    unsigned* candi = (unsigned*)w;
    convert_kernel<<<padded / 32, 256, 0, stream>>>(tk, tkbf, tnh2, C, padded);
    filter_mfma_fast<<<nchunks * 2, 512, 0, stream>>>(tkbf, keys, tnh2, thr, qn,
                                                      cnt, candi, C, cap);
    select_kernel<<<B, 256, 0, stream>>>(keys, tk, tv, cnt, candi, out, cap);
  } else {
    int cap = (int)((ws_size - fixed) / (4ull * (size_t)B));
    if (cap > MAXCAP) cap = MAXCAP;
    if (cap < 1) cap = 1;
    unsigned* candi = (unsigned*)w;
    filter_mfma_kernel<<<nchunks * 2, 512, 0, stream>>>(keys, tk, thr, qn,
                                                        cnt, candi, C, cap);
    select_kernel<<<B, 256, 0, stream>>>(keys, tk, tv, cnt, candi, out, cap);
  }
}

// Round 8
// 459.042 us; speedup vs baseline: 1.1150x; 1.0734x over previous
//
#include <hip/hip_runtime.h>
#include <math.h>

// kNN (B=1024, C=500000, D=64) + inverse-distance weighting, top-50.
// R8: single-pass filter. 1024-thr blocks (16 waves x 64 queries = all 1024
// queries), 245 blocks = ~1/CU. Staging = async global_load_lds width-16 from
// a pre-swizzled bf16 table (convert_kernel), double-buffered, 1 barrier per
// 128-row stage. Register thresholds in epilogue. qthresh=R5, select=R6/R7.

#define DELTA_SMOOTH 1e-3f
#define K_NEIGH 50
#define MAXCAP 8192
#define SAMPLE 2048
#define SAMPLE_TARGET 6
#define NBINS 256
#define MARGIN 0.75f       // bf16 dot worst-case error margin (d2 units)
#define MARGIN_Q 26        // select margin in d2q quanta: 2*(0.75+1/16)*16
#define RPB 2048           // table rows per filter block (single query pass)
#define NQ 1024            // queries (all) per filter block
#define SDEPTH 12          // LDS staging slots per query; lambda~6
#define LW 768             // select rescore list size
#define CVL 4096           // select LDS candidate cache
// fallback filter constants (R5 structure)
#define FQTILE 512
#define FRPB 1024
#define FSDEPTH 8

typedef __attribute__((ext_vector_type(8))) short short8;
typedef __attribute__((ext_vector_type(4))) float f32x4;
typedef __attribute__((address_space(1))) const unsigned int g_u32;
typedef __attribute__((address_space(3))) unsigned int l_u32;

__device__ __forceinline__ unsigned f2bf(float f) {
  unsigned u = __float_as_uint(f);
  return ((u + 0x7fffu + ((u >> 16) & 1u)) >> 16) & 0xffffu;
}

// ---------------- Kernel 0: table -> bf16 swizzled 128-row tiles + halved norms ----------------
// Row r chunk c (8 bf16 = 16 B) at uint4 index (r>>7)*1024 + (r&127)*8 + (c^(r&7)).
// A 128-row tile is a contiguous 16 KB segment whose byte image IS the LDS
// staging layout (global_load_lds copies it verbatim).
__global__ __launch_bounds__(256) void convert_kernel(
    const float* __restrict__ tk, uint4* __restrict__ tkbf,
    float* __restrict__ tnh2, int C, int padded) {
  int t = blockIdx.x * 256 + threadIdx.x;   // (row, chunk) id
  int r = t >> 3;
  if (r >= padded) return;
  int c = t & 7;
  int rs = r < C ? r : C - 1;
  const float4* src = (const float4*)(tk + (size_t)rs * 64 + c * 8);
  float4 a = src[0], b = src[1];
  float sq = a.x * a.x + a.y * a.y + a.z * a.z + a.w * a.w
           + b.x * b.x + b.y * b.y + b.z * b.z + b.w * b.w;
  sq += __shfl_xor(sq, 1); sq += __shfl_xor(sq, 2); sq += __shfl_xor(sq, 4);
  if (c == 0) tnh2[r] = sq * 0.5f;
  uint4 u;
  u.x = f2bf(a.x) | (f2bf(a.y) << 16);
  u.y = f2bf(a.z) | (f2bf(a.w) << 16);
  u.z = f2bf(b.x) | (f2bf(b.y) << 16);
  u.w = f2bf(b.z) | (f2bf(b.w) << 16);
  tkbf[(size_t)(r >> 7) * 1024 + (r & 127) * 8 + (c ^ (r & 7))] = u;
}

// ---------------- Kernel 1: per-query radius (R5 version) ----------------
__global__ __launch_bounds__(256) void qthresh_kernel(
    const float* __restrict__ keys, const float* __restrict__ tk,
    float* __restrict__ thr, float* __restrict__ qnorm, int C) {
  int q = blockIdx.x;
  __shared__ __align__(16) float kq[64];
  __shared__ unsigned hist[NBINS];
  __shared__ float qn_sh;
  __shared__ unsigned wsum[4];
  __shared__ int bstar_sh;
  int tid = threadIdx.x;
  int lane = tid & 63;
  int wid = tid >> 6;
  if (tid < 64) kq[tid] = keys[(size_t)q * 64 + tid];
  hist[tid] = 0u;
  if (tid == 0) bstar_sh = NBINS - 1;
  __syncthreads();
  if (tid < 64) {
    float v = kq[tid];
    float s = v * v;
    #pragma unroll
    for (int off = 32; off > 0; off >>= 1) s += __shfl_down(s, off);
    if (tid == 0) qn_sh = s;
  }
  __syncthreads();
  float qn = qn_sh;
  int kc = lane & 3;
  const float4* kq4 = (const float4*)kq;
  float4 kf[4];
  #pragma unroll
  for (int j = 0; j < 4; ++j) kf[j] = kq4[kc * 4 + j];
  int S = SAMPLE < C ? SAMPLE : C;
  for (int r = wid * (S >> 2) + (lane >> 2); r < (wid + 1) * (S >> 2); r += 16) {
    const float4* trow = (const float4*)(tk + (size_t)r * 64 + kc * 16);
    float a0 = 0.f, a1 = 0.f, sq = 0.f;
    #pragma unroll
    for (int j = 0; j < 4; ++j) {
      float4 tvv = trow[j];
      float4 kv = kf[j];
      a0 += kv.x * tvv.x + kv.y * tvv.y;
      a1 += kv.z * tvv.z + kv.w * tvv.w;
      sq += tvv.x * tvv.x + tvv.y * tvv.y + tvv.z * tvv.z + tvv.w * tvv.w;
    }
    float s = a0 + a1;
    s += __shfl_xor(s, 1); s += __shfl_xor(s, 2);
    sq += __shfl_xor(sq, 1); sq += __shfl_xor(sq, 2);
    if (kc == 0) {
      float d2 = qn + sq - 2.f * s;
      int b = (int)d2;
      b = b < 0 ? 0 : (b > NBINS - 1 ? NBINS - 1 : b);
      atomicAdd(&hist[b], 1u);
    }
  }
  __syncthreads();
  unsigned h = hist[tid];
  unsigned p = h;
  #pragma unroll
  for (int off = 1; off < 64; off <<= 1) {
    unsigned v = __shfl_up(p, off);
    if (lane >= off) p += v;
  }
  if (lane == 63) wsum[wid] = p;
  __syncthreads();
  unsigned add = 0;
  for (int w2 = 0; w2 < wid; ++w2) add += wsum[w2];
  p += add;
  if (p >= (unsigned)SAMPLE_TARGET && p - h < (unsigned)SAMPLE_TARGET) bstar_sh = tid;
  __syncthreads();
  if (tid == 0) {
    thr[q] = (float)(bstar_sh + 1) + MARGIN - qn;
    qnorm[q] = qn;
  }
}

// ---------------- Kernel 2a: single-pass async-staged bf16 MFMA filter ----------------
// 16 waves x 64 queries (4 m-tiles each) = 1024 queries; RPB=2048 rows/block.
// Stage = 128 rows (16 KB) via global_load_lds(16B) per thread, dbuf,
// 1 barrier/stage. hit <=> acc + thr/2 > tn/2 (register thresholds).
__global__ __launch_bounds__(1024, 4) void filter_mfma_fast(
    const uint4* __restrict__ tkbf, const float* __restrict__ keys,
    const float* __restrict__ tnh2, const float* __restrict__ thr,
    const float* __restrict__ qnorm, int* __restrict__ cnt,
    unsigned* __restrict__ candi, int C, int cap) {
  __shared__ __align__(16) uint4 bstage[2][1024];         // 32 KB dbuf
  __shared__ float tnh_lds[RPB];                          // 8 KB
  __shared__ float thr_lds[NQ];                           // 4 KB
  __shared__ float qn_lds[NQ];                            // 4 KB
  __shared__ unsigned scnt[NQ];                           // 4 KB
  __shared__ unsigned sbuf[NQ * SDEPTH];                  // 48 KB

  int tid = threadIdx.x;
  int rstart = blockIdx.x * RPB;

  tnh_lds[tid] = tnh2[rstart + tid];
  tnh_lds[tid + 1024] = tnh2[rstart + tid + 1024];
  thr_lds[tid] = thr[tid];
  qn_lds[tid] = qnorm[tid];
  scnt[tid] = 0u;

  int lane = tid & 63;
  int wq = tid >> 6;       // 0..15
  int l15 = lane & 15;
  int quad = lane >> 4;

  // A fragments: 4 m-tiles; A[m=l15][k=s*32+quad*8+j] (verified R2-R7)
  short8 afrag[4][2];
  #pragma unroll
  for (int mt = 0; mt < 4; ++mt) {
    const float* kp = keys + (size_t)(wq * 64 + mt * 16 + l15) * 64 + quad * 8;
    #pragma unroll
    for (int s = 0; s < 2; ++s) {
      float4 x = *(const float4*)(kp + s * 32);
      float4 y = *(const float4*)(kp + s * 32 + 4);
      short8 a;
      a[0] = (short)f2bf(x.x); a[1] = (short)f2bf(x.y);
      a[2] = (short)f2bf(x.z); a[3] = (short)f2bf(x.w);
      a[4] = (short)f2bf(y.x); a[5] = (short)f2bf(y.y);
      a[6] = (short)f2bf(y.z); a[7] = (short)f2bf(y.w);
      afrag[mt][s] = a;
    }
  }

  // staging pointers: stage st copies tile (rstart/128 + st) verbatim
  const uint4* gbase = tkbf + (size_t)(rstart >> 7) * 1024;
  const int ITERS = RPB / 128;   // 16

  // issue stage 0
  __builtin_amdgcn_global_load_lds((g_u32*)(gbase + tid), (l_u32*)(&bstage[0][wq * 64]), 16, 0, 0);
  __syncthreads();   // drains stage-0 DMA + publishes tnh/thr/qn/scnt

  // register thresholds (halved); read after barrier
  float htr[4][4], hmax[4];
  #pragma unroll
  for (int mt = 0; mt < 4; ++mt) {
    #pragma unroll
    for (int r = 0; r < 4; ++r)
      htr[mt][r] = thr_lds[wq * 64 + mt * 16 + quad * 4 + r] * 0.5f;
    hmax[mt] = fmaxf(fmaxf(htr[mt][0], htr[mt][1]), fmaxf(htr[mt][2], htr[mt][3]));
  }

  f32x4 zero4 = {0.f, 0.f, 0.f, 0.f};

  for (int it = 0; it < ITERS; ++it) {
    if (it + 1 < ITERS) {
      __builtin_amdgcn_global_load_lds((g_u32*)(gbase + (size_t)(it + 1) * 1024 + tid),
                                       (l_u32*)(&bstage[(it + 1) & 1][wq * 64]), 16, 0, 0);
    }
    const unsigned char* buf = (const unsigned char*)bstage[it & 1];
    #pragma unroll
    for (int sub = 0; sub < 2; ++sub) {
      #pragma unroll
      for (int half = 0; half < 2; ++half) {
        // B fragments: row nloc, chunk c=s*4+quad, swizzled byte address
        short8 b[2][2];
        #pragma unroll
        for (int tt = 0; tt < 2; ++tt) {
          int nloc = half * 32 + tt * 16 + l15;
          #pragma unroll
          for (int s = 0; s < 2; ++s) {
            int c = s * 4 + quad;
            unsigned addr = (unsigned)(sub * 8192 + nloc * 128 + ((c ^ (nloc & 7)) << 4));
            b[tt][s] = *(const short8*)(buf + addr);
          }
        }
        f32x4 acc[4][2];
        #pragma unroll
        for (int mt = 0; mt < 4; ++mt) {
          #pragma unroll
          for (int tt = 0; tt < 2; ++tt) {
            f32x4 a0 = __builtin_amdgcn_mfma_f32_16x16x32_bf16(afrag[mt][0], b[tt][0], zero4, 0, 0, 0);
            acc[mt][tt] = __builtin_amdgcn_mfma_f32_16x16x32_bf16(afrag[mt][1], b[tt][1], a0, 0, 0, 0);
          }
        }
        #pragma unroll
        for (int tt = 0; tt < 2; ++tt) {
          int rloc = it * 128 + sub * 64 + half * 32 + tt * 16 + l15;
          float tnh = tnh_lds[rloc];
          int n = rstart + rloc;
          #pragma unroll
          for (int mt = 0; mt < 4; ++mt) {
            float mx4 = fmaxf(fmaxf(acc[mt][tt][0], acc[mt][tt][1]),
                              fmaxf(acc[mt][tt][2], acc[mt][tt][3]));
            if (mx4 + hmax[mt] > tnh) {
              #pragma unroll
              for (int r = 0; r < 4; ++r) {
                if (acc[mt][tt][r] + htr[mt][r] > tnh && n < C) {
                  int ql = wq * 64 + mt * 16 + quad * 4 + r;
                  float d2f = 2.f * (tnh - acc[mt][tt][r]) + qn_lds[ql];
                  int d2q = (int)(d2f * 16.f);
                  d2q = d2q < 0 ? 0 : (d2q > 8191 ? 8191 : d2q);
                  unsigned v = ((unsigned)d2q << 19) | (unsigned)n;
                  unsigned p = atomicAdd(&scnt[ql], 1u);
                  if (p < SDEPTH) {
                    sbuf[ql * SDEPTH + p] = v;
                  } else {
                    int g = atomicAdd(&cnt[ql], 1);
                    if (g < cap) candi[(size_t)ql * cap + g] = v;
                  }
                }
              }
            }
          }
        }
      }
    }
    __syncthreads();   // drains prefetch DMA; syncs before buffer reuse
  }
  // flush: one global atomic per query
  int m = (int)scnt[tid];
  if (m > SDEPTH) m = SDEPTH;
  if (m > 0) {
    int base = atomicAdd(&cnt[tid], m);
    for (int j = 0; j < m; ++j) {
      int g = base + j;
      if (g < cap) candi[(size_t)tid * cap + g] = sbuf[tid * SDEPTH + j];
    }
  }
}

// ---------------- Kernel 2b: FALLBACK filter (R5 verbatim; in-loop convert) ----------------
__global__ __launch_bounds__(512, 4) void filter_fallback(
    const float* __restrict__ keys, const float* __restrict__ tk,
    const float* __restrict__ thr, const float* __restrict__ qnorm,
    int* __restrict__ cnt, unsigned* __restrict__ candi, int C, int cap) {
  __shared__ float tnstage[64];
  __shared__ float thr_lds[FQTILE];
  __shared__ float qn_lds[FQTILE];
  __shared__ unsigned scnt[FQTILE];
  __shared__ unsigned sbuf[FQTILE * FSDEPTH];
  __shared__ __align__(16) unsigned char bstage[64 * 128];

  int tid = threadIdx.x;
  int qt = blockIdx.x & 1;
  int chunk = blockIdx.x >> 1;
  int qbase = qt * FQTILE;
  int rstart = chunk * FRPB;

  thr_lds[tid] = thr[qbase + tid];
  qn_lds[tid] = qnorm[qbase + tid];
  scnt[tid] = 0u;

  int lane = tid & 63;
  int wq = tid >> 6;
  int l15 = lane & 15;
  int quad = lane >> 4;

  short8 afrag[4][2];
  #pragma unroll
  for (int mt = 0; mt < 4; ++mt) {
    const float* kp = keys + (size_t)(qbase + wq * 64 + mt * 16 + l15) * 64 + quad * 8;
    #pragma unroll
    for (int s = 0; s < 2; ++s) {
      float4 x = *(const float4*)(kp + s * 32);
      float4 y = *(const float4*)(kp + s * 32 + 4);
      short8 a;
      a[0] = (short)f2bf(x.x); a[1] = (short)f2bf(x.y);
      a[2] = (short)f2bf(x.z); a[3] = (short)f2bf(x.w);
      a[4] = (short)f2bf(y.x); a[5] = (short)f2bf(y.y);
      a[6] = (short)f2bf(y.z); a[7] = (short)f2bf(y.w);
      afrag[mt][s] = a;
    }
  }
  __syncthreads();

  float hq[4];
  #pragma unroll
  for (int mt = 0; mt < 4; ++mt) {
    float h0 = thr_lds[wq * 64 + mt * 16 + quad * 4 + 0];
    float h1 = thr_lds[wq * 64 + mt * 16 + quad * 4 + 1];
    float h2 = thr_lds[wq * 64 + mt * 16 + quad * 4 + 2];
    float h3 = thr_lds[wq * 64 + mt * 16 + quad * 4 + 3];
    hq[mt] = fmaxf(fmaxf(h0, h1), fmaxf(h2, h3));
  }

  int srow = tid >> 3;
  int scol = tid & 7;
  unsigned sbyte = (unsigned)(srow * 128 + ((scol ^ (srow & 7)) << 4));

  const int ITERS = FRPB / 64;
  int r0 = rstart + srow; if (r0 > C - 1) r0 = C - 1;
  float4 pa = *(const float4*)(tk + (size_t)r0 * 64 + scol * 8);
  float4 pb = *(const float4*)(tk + (size_t)r0 * 64 + scol * 8 + 4);

  f32x4 zero4 = {0.f, 0.f, 0.f, 0.f};

  for (int it = 0; it < ITERS; ++it) {
    float part = pa.x * pa.x + pa.y * pa.y + pa.z * pa.z + pa.w * pa.w
               + pb.x * pb.x + pb.y * pb.y + pb.z * pb.z + pb.w * pb.w;
    part += __shfl_xor(part, 1);
    part += __shfl_xor(part, 2);
    part += __shfl_xor(part, 4);
    if ((tid & 7) == 0) tnstage[srow] = part;
    uint4 u;
    u.x = f2bf(pa.x) | (f2bf(pa.y) << 16);
    u.y = f2bf(pa.z) | (f2bf(pa.w) << 16);
    u.z = f2bf(pb.x) | (f2bf(pb.y) << 16);
    u.w = f2bf(pb.z) | (f2bf(pb.w) << 16);
    *(uint4*)(bstage + sbyte) = u;
    __syncthreads();
    if (it + 1 < ITERS) {
      int rn = rstart + (it + 1) * 64 + srow; if (rn > C - 1) rn = C - 1;
      pa = *(const float4*)(tk + (size_t)rn * 64 + scol * 8);
      pb = *(const float4*)(tk + (size_t)rn * 64 + scol * 8 + 4);
    }
    #pragma unroll
    for (int half = 0; half < 2; ++half) {
      short8 b[2][2];
      #pragma unroll
      for (int tt = 0; tt < 2; ++tt) {
        int nloc = half * 32 + tt * 16 + l15;
        #pragma unroll
        for (int s = 0; s < 2; ++s) {
          int c = s * 4 + quad;
          unsigned addr = (unsigned)(nloc * 128 + ((c ^ (nloc & 7)) << 4));
          b[tt][s] = *(const short8*)(bstage + addr);
        }
      }
      f32x4 acc[4][2];
      #pragma unroll
      for (int mt = 0; mt < 4; ++mt) {
        #pragma unroll
        for (int tt = 0; tt < 2; ++tt) {
          f32x4 a0 = __builtin_amdgcn_mfma_f32_16x16x32_bf16(afrag[mt][0], b[tt][0], zero4, 0, 0, 0);
          acc[mt][tt] = __builtin_amdgcn_mfma_f32_16x16x32_bf16(afrag[mt][1], b[tt][1], a0, 0, 0, 0);
        }
      }
      #pragma unroll
      for (int tt = 0; tt < 2; ++tt) {
        float tn = tnstage[half * 32 + tt * 16 + l15];
        int n = rstart + it * 64 + half * 32 + tt * 16 + l15;
        #pragma unroll
        for (int mt = 0; mt < 4; ++mt) {
          float d0 = fmaf(-2.f, acc[mt][tt][0], tn);
          float d1 = fmaf(-2.f, acc[mt][tt][1], tn);
          float d2 = fmaf(-2.f, acc[mt][tt][2], tn);
          float d3 = fmaf(-2.f, acc[mt][tt][3], tn);
          float mn4 = fminf(fminf(d0, d1), fminf(d2, d3));
          if (mn4 < hq[mt]) {
            float dd[4] = {d0, d1, d2, d3};
            #pragma unroll
            for (int r = 0; r < 4; ++r) {
              int ql = wq * 64 + mt * 16 + quad * 4 + r;
              if (dd[r] < thr_lds[ql] && n < C) {
                float d2f = dd[r] + qn_lds[ql];
                int d2q = (int)(d2f * 16.f);
                d2q = d2q < 0 ? 0 : (d2q > 8191 ? 8191 : d2q);
                unsigned v = ((unsigned)d2q << 19) | (unsigned)n;
                unsigned p = atomicAdd(&scnt[ql], 1u);
                if (p < FSDEPTH) {
                  sbuf[ql * FSDEPTH + p] = v;
                } else {
                  int g = atomicAdd(&cnt[qbase + ql], 1);
                  if (g < cap) candi[(size_t)(qbase + ql) * cap + g] = v;
                }
              }
            }
          }
        }
      }
    }
    __syncthreads();
  }
  int m = (int)scnt[tid];
  if (m > FSDEPTH) m = FSDEPTH;
  if (m > 0) {
    int base = atomicAdd(&cnt[qbase + tid], m);
    for (int j = 0; j < m; ++j) {
      int g = base + j;
      if (g < cap) candi[(size_t)(qbase + tid) * cap + g] = sbuf[tid * FSDEPTH + j];
    }
  }
}

// ---------------- Kernel 3: select (LDS-cached list; R6/R7 version) ----------------
__global__ __launch_bounds__(256) void select_kernel(
    const float* __restrict__ keys, const float* __restrict__ tk,
    const float* __restrict__ tv, const int* __restrict__ cnt,
    const unsigned* __restrict__ candi, float* __restrict__ out, int cap) {
  int q = blockIdx.x;
  __shared__ unsigned cvl[CVL];
  __shared__ unsigned hist[NBINS];
  __shared__ unsigned wsum[4];
  __shared__ unsigned minq_sh;
  __shared__ int b50_sh;
  __shared__ int lidx[LW];
  __shared__ unsigned ed2[LW];
  __shared__ int m_sh;
  __shared__ float redw[4], redwv[4];
  int tid = threadIdx.x;
  int lane = tid & 63;
  int wid = tid >> 6;
  int n = cnt[q];
  if (n > cap) n = cap;
  hist[tid] = 0u;
  if (tid == 0) { minq_sh = 0xffffffffu; b50_sh = NBINS - 1; m_sh = 0; }
  __syncthreads();
  const unsigned* cv = candi + (size_t)q * cap;
  unsigned mn = 0xffffffffu;
  for (int i = tid; i < n; i += 256) {
    unsigned v = cv[i];
    if (i < CVL) cvl[i] = v;
    unsigned d = v >> 19; if (d < mn) mn = d;
  }
  #pragma unroll
  for (int off = 1; off < 64; off <<= 1) { unsigned o = __shfl_xor(mn, off); if (o < mn) mn = o; }
  if (lane == 0) atomicMin(&minq_sh, mn);
  __syncthreads();
  unsigned base = minq_sh;
  for (int i = tid; i < n; i += 256) {
    unsigned v = (i < CVL) ? cvl[i] : cv[i];
    unsigned d = (v >> 19) - base;
    unsigned b = d >> 1; if (b > NBINS - 1) b = NBINS - 1;
    atomicAdd(&hist[b], 1u);
  }
  __syncthreads();
  unsigned h = hist[tid];
  unsigned p = h;
  #pragma unroll
  for (int off = 1; off < 64; off <<= 1) {
    unsigned v = __shfl_up(p, off);
    if (lane >= off) p += v;
  }
  if (lane == 63) wsum[wid] = p;
  __syncthreads();
  unsigned add = 0;
  for (int w2 = 0; w2 < wid; ++w2) add += wsum[w2];
  p += add;
  if (p >= (unsigned)K_NEIGH && p - h < (unsigned)K_NEIGH) b50_sh = tid;
  __syncthreads();
  unsigned Tq = base + (((unsigned)(b50_sh + 1)) << 1) + MARGIN_Q;
  for (int i = tid; i < n; i += 256) {
    unsigned v = (i < CVL) ? cvl[i] : cv[i];
    if ((v >> 19) <= Tq) {
      int p2 = atomicAdd(&m_sh, 1);
      if (p2 < LW) lidx[p2] = (int)(v & 0x7ffffu);
    }
  }
  __syncthreads();
  int m = m_sh; if (m > LW) m = LW;
  float kqv = keys[(size_t)q * 64 + lane];
  for (int i0 = wid * 4; i0 < m; i0 += 16) {
    int mm = m - i0; if (mm > 4) mm = 4;
    int idx[4]; float t[4];
    for (int u = 0; u < mm; ++u) idx[u] = lidx[i0 + u];
    for (int u = 0; u < mm; ++u) t[u] = tk[(size_t)idx[u] * 64 + lane];
    for (int u = 0; u < mm; ++u) {
      float d = t[u] - kqv;
      float s = d * d;
      #pragma unroll
      for (int off = 1; off < 64; off <<= 1) s += __shfl_xor(s, off);
      if (lane == 0) ed2[i0 + u] = __float_as_uint(s);
    }
  }
  __syncthreads();
  float accw = 0.f, accwv = 0.f;
  for (int i = tid; i < m; i += 256) {
    unsigned long long key = ((unsigned long long)ed2[i] << 19) | (unsigned)lidx[i];
    int rank = 0;
    for (int j = 0; j < m; ++j) {
      unsigned long long kj = ((unsigned long long)ed2[j] << 19) | (unsigned)lidx[j];
      rank += (kj < key) ? 1 : 0;
    }
    if (rank < K_NEIGH) {
      float d2 = __uint_as_float(ed2[i]);
      float w = 1.f / (d2 + DELTA_SMOOTH);
      accw += w;
      accwv += w * tv[lidx[i]];
    }
  }
  #pragma unroll
  for (int off = 1; off < 64; off <<= 1) {
    accw += __shfl_xor(accw, off);
    accwv += __shfl_xor(accwv, off);
  }
  if (lane == 0) { redw[wid] = accw; redwv[wid] = accwv; }
  __syncthreads();
  if (tid == 0) {
    float sw = redw[0] + redw[1] + redw[2] + redw[3];
    float swv = redwv[0] + redwv[1] + redwv[2] + redwv[3];
    out[q] = swv / sw;
  }
}

extern "C" void kernel_launch(void* const* d_in, const int* in_sizes, int n_in,
                              void* d_out, int out_size, void* d_ws, size_t ws_size,
                              hipStream_t stream) {
  const float* keys = (const float*)d_in[0];   // [B,64]
  const float* tk   = (const float*)d_in[1];   // [C,64]
  const float* tv   = (const float*)d_in[2];   // [C]
  float* out = (float*)d_out;
  int B = in_sizes[0] / 64;   // 1024
  int C = in_sizes[2];        // 500000 (< 2^19 for packing)

  int nchunks = (C + RPB - 1) / RPB;   // 245
  int padded = nchunks * RPB;          // 501760

  char* w = (char*)d_ws;
  float* thr = (float*)w;  w += (size_t)B * 4;
  float* qn  = (float*)w;  w += (size_t)B * 4;
  int*   cnt = (int*)w;    w += (size_t)B * 4;

  size_t fixed = (size_t)(w - (char*)d_ws);
  size_t fast_need = fixed + (size_t)padded * 128 + (size_t)padded * 4
                   + 2048ull * (size_t)B * 4;
  bool fast = ws_size >= fast_need;

  hipMemsetAsync(cnt, 0, (size_t)B * 4, stream);
  qthresh_kernel<<<B, 256, 0, stream>>>(keys, tk, thr, qn, C);

  if (fast) {
    uint4* tkbf  = (uint4*)w;             w += (size_t)padded * 128;
    float* tnh2  = (float*)w;             w += (size_t)padded * 4;
    size_t used = (size_t)(w - (char*)d_ws);
    int cap = (int)((ws_size - used) / (4ull * (size_t)B));
    if (cap > MAXCAP) cap = MAXCAP;
    unsigned* candi = (unsigned*)w;
    convert_kernel<<<padded / 32, 256, 0, stream>>>(tk, tkbf, tnh2, C, padded);
    filter_mfma_fast<<<nchunks, 1024, 0, stream>>>(tkbf, keys, tnh2, thr, qn,
                                                   cnt, candi, C, cap);
    select_kernel<<<B, 256, 0, stream>>>(keys, tk, tv, cnt, candi, out, cap);
  } else {
    int cap = (int)((ws_size - fixed) / (4ull * (size_t)B));
    if (cap > MAXCAP) cap = MAXCAP;
    if (cap < 1) cap = 1;
    unsigned* candi = (unsigned*)w;
    int fchunks = (C + FRPB - 1) / FRPB;
    filter_fallback<<<fchunks * 2, 512, 0, stream>>>(keys, tk, thr, qn,
                                                     cnt, candi, C, cap);
    select_kernel<<<B, 256, 0, stream>>>(keys, tk, tv, cnt, candi, out, cap);
  }
}